// Round 4
// baseline (992.241 us; speedup 1.0000x reference)
//
#include <hip/hip_runtime.h>
#include <cstddef>

#define NS 512
#define NL 5
#define NT 20
#define NE 768
#define NH 64
#define NG 256   // 4*H

__device__ __forceinline__ float sigf(float x) { return 1.0f / (1.0f + expf(-x)); }
__device__ __forceinline__ float bcast(float v, int k) {
    return __int_as_float(__builtin_amdgcn_readlane(__float_as_int(v), k));
}

typedef __attribute__((ext_vector_type(8))) short short8v;   // 8 bf16 = 4 VGPR
typedef __attribute__((ext_vector_type(4))) float f32x4;

// round-to-nearest-ish fp32 -> bf16 split: x ~= hi + lo, residual ~2^-18 |x|
__device__ __forceinline__ void split_bf16(float x, unsigned short& hi, unsigned short& lo) {
    unsigned int bx = __float_as_uint(x);
    unsigned int h = (bx + 0x8000u) >> 16;
    hi = (unsigned short)h;
    float r = x - __uint_as_float(h << 16);
    lo = (unsigned short)((__float_as_uint(r) + 0x8000u) >> 16);
}

// ---------------------------------------------------------------------------
// Kernel 1 v5 (MFMA, 3xbf16 split): u[s][t][l][g] = x-row . Uall[s][:,g] + bU
// v4 -> v5: VGPR <= 128 (launch_bounds 512,4) so 2 blocks/CU fit and all 512
// blocks run in ONE round (v4's ~150 VGPR forced 1 block/CU = 2 rounds).
// Register cuts: A-fragments reloaded per (ni,mi) instead of held (LDS b128
// per wave-step 22 -> 46, still under the HBM cycle budget); derived LDS
// offsets (+256/+512) instead of stored. Next-step global loads now issue
// BEFORE the first barrier so HBM latency hides under barrier+MFMA+other
// block instead of just the 233-cyc MFMA section.
// ---------------------------------------------------------------------------
__global__ __launch_bounds__(512, 4) void k_gemm_u(
    const float* __restrict__ x, const float* __restrict__ U,
    const float* __restrict__ bU, float* __restrict__ u)
{
    __shared__ unsigned short Af[8 * 2 * 64 * 8];    // [mtile][hl][lane][8] = 16 KB
    __shared__ unsigned short Bf[16 * 2 * 64 * 8];   // [ntile][hl][lane][8] = 32 KB
    const int s = blockIdx.x;
    const int tid = threadIdx.x;
    const int wave = tid >> 6, lane = tid & 63;
    const int wm = wave & 1, wn = wave >> 1;
    const float* xg = x + (size_t)s * (NL * NT * NE);
    const float* Ug = U + (size_t)s * (NE * NG);

    f32x4 acc[4][4] = {};

    // A staging: thread -> chunk (row, b): 8 floats x[row][k0+8b .. +7]
    const int arow = tid >> 2, ab = tid & 3;
    const unsigned int a_off0 = (((unsigned)(arow >> 4) * 2 + 0) * 64 + ((arow & 15) + 16 * ab)) * 8;
    // hi at a_off0, lo at a_off0 + 512
    // B staging: thread -> chunks (col, bq1) and (col, bq1+2)
    const int bcol = tid & 255, bq1 = tid >> 8;
    const unsigned int b_off1h = (unsigned)(bcol >> 4) * 2 * 64 * 8 + ((bcol & 15) + 16 * bq1) * 8;
    // lo at +512; second chunk at +256 (16*(bq1+2) vs 16*bq1 => +256 shorts)

    float av[8], bv1[8], bv2[8];
    // prologue: loads for step 0
    {
        const float* pa = xg + (size_t)arow * NE + ab * 8;
        if (arow < 100) {
            float4 q0 = *(const float4*)pa, q1 = *(const float4*)(pa + 4);
            av[0]=q0.x; av[1]=q0.y; av[2]=q0.z; av[3]=q0.w;
            av[4]=q1.x; av[5]=q1.y; av[6]=q1.z; av[7]=q1.w;
        } else {
            #pragma unroll
            for (int j = 0; j < 8; ++j) av[j] = 0.0f;
        }
        const float* pb = Ug + bcol;
        #pragma unroll
        for (int j = 0; j < 8; ++j) {
            bv1[j] = pb[(size_t)(8 * bq1 + j) * NG];
            bv2[j] = pb[(size_t)(8 * bq1 + 16 + j) * NG];
        }
    }

    for (int st = 0; st < 24; ++st) {
        // ---- split staged registers into hi/lo bf16, write fragment LDS ----
        {
            unsigned short h[8], l[8];
            #pragma unroll
            for (int j = 0; j < 8; ++j) split_bf16(av[j], h[j], l[j]);
            uint4 ph, pl;
            ph.x = h[0] | (h[1] << 16); ph.y = h[2] | (h[3] << 16);
            ph.z = h[4] | (h[5] << 16); ph.w = h[6] | (h[7] << 16);
            pl.x = l[0] | (l[1] << 16); pl.y = l[2] | (l[3] << 16);
            pl.z = l[4] | (l[5] << 16); pl.w = l[6] | (l[7] << 16);
            *(uint4*)&Af[a_off0]       = ph;
            *(uint4*)&Af[a_off0 + 512] = pl;
            #pragma unroll
            for (int j = 0; j < 8; ++j) split_bf16(bv1[j], h[j], l[j]);
            ph.x = h[0] | (h[1] << 16); ph.y = h[2] | (h[3] << 16);
            ph.z = h[4] | (h[5] << 16); ph.w = h[6] | (h[7] << 16);
            pl.x = l[0] | (l[1] << 16); pl.y = l[2] | (l[3] << 16);
            pl.z = l[4] | (l[5] << 16); pl.w = l[6] | (l[7] << 16);
            *(uint4*)&Bf[b_off1h]       = ph;
            *(uint4*)&Bf[b_off1h + 512] = pl;
            #pragma unroll
            for (int j = 0; j < 8; ++j) split_bf16(bv2[j], h[j], l[j]);
            ph.x = h[0] | (h[1] << 16); ph.y = h[2] | (h[3] << 16);
            ph.z = h[4] | (h[5] << 16); ph.w = h[6] | (h[7] << 16);
            pl.x = l[0] | (l[1] << 16); pl.y = l[2] | (l[3] << 16);
            pl.z = l[4] | (l[5] << 16); pl.w = l[6] | (l[7] << 16);
            *(uint4*)&Bf[b_off1h + 256] = ph;
            *(uint4*)&Bf[b_off1h + 768] = pl;
        }
        // ---- issue next step's global loads BEFORE the barrier ----
        if (st + 1 < 24) {
            const int k0 = (st + 1) * 32;
            const float* pa = xg + (size_t)arow * NE + k0 + ab * 8;
            if (arow < 100) {
                float4 q0 = *(const float4*)pa, q1 = *(const float4*)(pa + 4);
                av[0]=q0.x; av[1]=q0.y; av[2]=q0.z; av[3]=q0.w;
                av[4]=q1.x; av[5]=q1.y; av[6]=q1.z; av[7]=q1.w;
            } else {
                #pragma unroll
                for (int j = 0; j < 8; ++j) av[j] = 0.0f;
            }
            const float* pb = Ug + (size_t)k0 * NG + bcol;
            #pragma unroll
            for (int j = 0; j < 8; ++j) {
                bv1[j] = pb[(size_t)(8 * bq1 + j) * NG];
                bv2[j] = pb[(size_t)(8 * bq1 + 16 + j) * NG];
            }
        }
        __syncthreads();

        // ---- MFMA: ni outer (B held), mi inner (A reloaded per use) ----
        #pragma unroll
        for (int ni = 0; ni < 4; ++ni) {
            const unsigned int nt = wn * 4 + ni;
            short8v bh = *(const short8v*)&Bf[(nt * 2 + 0) * 512 + lane * 8];
            short8v bl = *(const short8v*)&Bf[(nt * 2 + 1) * 512 + lane * 8];
            #pragma unroll
            for (int mi = 0; mi < 4; ++mi) {
                const unsigned int mt = wm * 4 + mi;
                short8v ah = *(const short8v*)&Af[(mt * 2 + 0) * 512 + lane * 8];
                short8v al = *(const short8v*)&Af[(mt * 2 + 1) * 512 + lane * 8];
                acc[mi][ni] = __builtin_amdgcn_mfma_f32_16x16x32_bf16(ah, bh, acc[mi][ni], 0, 0, 0);
                acc[mi][ni] = __builtin_amdgcn_mfma_f32_16x16x32_bf16(ah, bl, acc[mi][ni], 0, 0, 0);
                acc[mi][ni] = __builtin_amdgcn_mfma_f32_16x16x32_bf16(al, bh, acc[mi][ni], 0, 0, 0);
            }
        }
        __syncthreads();
    }

    // ---- epilogue: bias + scattered store (C/D: col=lane&15, row=4*(l>>4)+r) ----
    const int c_sub = 4 * (lane >> 4);
    #pragma unroll
    for (int ni = 0; ni < 4; ++ni) {
        const int gcol = wn * 64 + ni * 16 + (lane & 15);
        const float bb = bU[(size_t)s * NG + gcol];
        #pragma unroll
        for (int mi = 0; mi < 4; ++mi) {
            const int grow0 = wm * 64 + mi * 16 + c_sub;
            #pragma unroll
            for (int r = 0; r < 4; ++r) {
                const int grow = grow0 + r;
                if (grow < 100) {
                    const int ld = grow / 20, td = grow % 20;
                    u[(((size_t)s * NT + td) * NL + ld) * NG + gcol] = acc[mi][ni][r] + bb;
                }
            }
        }
    }
}

// ---------------------------------------------------------------------------
// Kernel 2 (unchanged this round; MFMA recurrence rewrite planned next)
// ---------------------------------------------------------------------------
#define WD    0        // 4096 fl; aliased by W1 after the recurrence
#define W1OFF 0
#define W2OFF 4096     // 4096 fl
#define FULLO 8192     // 6400 fl: o-gates [l][t][h]
#define HS    14592    // 320
#define TQ    14912    // 320: q, then hd
#define CA    15232    // 320: text_vec
#define GATES 15552    // 1280
#define TS    16832    // 100
#define SC    16932    // 100
#define B0    17032    // 64: b1
#define B1    17096    // 64: b2
#define BVV   17160    // 64: V
#define BV1   17224    // 1
#define SMTOT 17228    // 68912 B

__global__ __launch_bounds__(320, 3) void k_stock(
    const float* __restrict__ u, const float* __restrict__ ti,
    const float* __restrict__ Wall, const float* __restrict__ bWall,
    const float* __restrict__ Wd, const float* __restrict__ bWd,
    const float* __restrict__ W1, const float* __restrict__ b1,
    const float* __restrict__ W2, const float* __restrict__ b2,
    const float* __restrict__ V, const float* __restrict__ bV,
    const float* __restrict__ Wih, const float* __restrict__ bih,
    const float* __restrict__ bhh, const float* __restrict__ lin_w,
    const float* __restrict__ lin_b, float* __restrict__ out)
{
    __shared__ float sm[SMTOT];
    const int s = blockIdx.x;
    const int tid = threadIdx.x;
    const int lq = tid >> 6, hh = tid & 63;
    const int lane = hh;
    const float* ug = u + (size_t)s * NT * NL * NG;

    for (int i = tid; i < 1024; i += 320)
        *(float4*)&sm[WD + i * 4] = *(const float4*)(Wd + (size_t)s * 4096 + i * 4);
    for (int i = tid; i < 1024; i += 320)
        *(float4*)&sm[W2OFF + i * 4] = *(const float4*)(W2 + (size_t)s * 4096 + i * 4);
    if (tid < NH) {
        sm[B0 + tid]  = b1[(size_t)s * NH + tid];
        sm[B1 + tid]  = b2[(size_t)s * NH + tid];
        sm[BVV + tid] = V[(size_t)s * NH + tid];
    }
    if (tid == 0) sm[BV1] = bV[s];
    if (tid < NL * NT) sm[TS + tid] = ti[(size_t)s * NL * NT + tid];
    sm[HS + tid] = 0.0f;
    const float bwd_r = bWd[(size_t)s * NH + hh];
    float c_reg = 0.0f;
    float wall_r[NH];
    float bwall_r = 0.0f, uc[NL];
    if (tid < NG) {
        bwall_r = bWall[(size_t)s * NG + tid];
        const float* wp = Wall + (size_t)s * (NH * NG) + tid;
        #pragma unroll
        for (int k = 0; k < NH; ++k) wall_r[k] = wp[(size_t)k * NG];
        #pragma unroll
        for (int l = 0; l < NL; ++l) uc[l] = ug[(size_t)l * NG + tid];
    }
    __syncthreads();

    for (int t = 0; t < NT; ++t) {
        float un[NL];
        if (tid < NG) {
            if (t + 1 < NT) {
                #pragma unroll
                for (int l = 0; l < NL; ++l)
                    un[l] = ug[(size_t)((t + 1) * NL + l) * NG + tid];
            } else {
                #pragma unroll
                for (int l = 0; l < NL; ++l) un[l] = 0.0f;
            }
            float hreg[NL];
            #pragma unroll
            for (int l = 0; l < NL; ++l) hreg[l] = sm[HS + l * NH + lane];
            float gv[NL];
            #pragma unroll
            for (int l = 0; l < NL; ++l) gv[l] = bwall_r + uc[l];
            #pragma unroll
            for (int k = 0; k < NH; ++k) {
                float w = wall_r[k];
                #pragma unroll
                for (int l = 0; l < NL; ++l)
                    gv[l] += bcast(hreg[l], k) * w;
            }
            #pragma unroll
            for (int l = 0; l < NL; ++l)
                sm[GATES + l * NG + tid] = sigf(gv[l]);
        }
        float ssum = bwd_r;
        #pragma unroll
        for (int k = 0; k < NH; ++k)
            ssum += bcast(c_reg, k) * sm[WD + k * NH + hh];
        float cs1 = tanhf(ssum);
        float ca = c_reg - cs1 + cs1 * sm[TS + lq * NT + t];
        __syncthreads();
        {
            float f  = sm[GATES + lq * NG + hh];
            float ii = sm[GATES + lq * NG + 64 + hh];
            float oo = sm[GATES + lq * NG + 128 + hh];
            float ct = sm[GATES + lq * NG + 192 + hh];
            float cn = f * ca + ii * ct;
            c_reg = cn;
            sm[HS + tid] = oo * tanhf(cn);
            sm[FULLO + (lq * NT + t) * NH + hh] = oo;
        }
        __syncthreads();
        if (tid < NG) {
            #pragma unroll
            for (int l = 0; l < NL; ++l) uc[l] = un[l];
        }
    }

    for (int i = tid; i < 1024; i += 320)
        *(float4*)&sm[W1OFF + i * 4] = *(const float4*)(W1 + (size_t)s * 4096 + i * 4);
    __syncthreads();

    {
        float qv = sm[B0 + hh];
        for (int k4 = 0; k4 < NH; k4 += 4) {
            float4 hv = *(const float4*)&sm[HS + lq * NH + k4];
            qv += hv.x * sm[W1OFF + (k4 + 0) * NH + hh]
                + hv.y * sm[W1OFF + (k4 + 1) * NH + hh]
                + hv.z * sm[W1OFF + (k4 + 2) * NH + hh]
                + hv.w * sm[W1OFF + (k4 + 3) * NH + hh];
        }
        sm[TQ + tid] = qv;
    }
    __syncthreads();

    for (int lt = lq; lt < NL * NT; lt += 5) {
        int l = lt / NT;
        float v = sm[TQ + l * NH + lane] + sm[B1 + lane];
        for (int k4 = 0; k4 < NH; k4 += 4) {
            float4 fv = *(const float4*)&sm[FULLO + lt * NH + k4];
            v += fv.x * sm[W2OFF + (k4 + 0) * NH + lane]
               + fv.y * sm[W2OFF + (k4 + 1) * NH + lane]
               + fv.z * sm[W2OFF + (k4 + 2) * NH + lane]
               + fv.w * sm[W2OFF + (k4 + 3) * NH + lane];
        }
        v = tanhf(v) * sm[BVV + lane];
        #pragma unroll
        for (int m = 32; m > 0; m >>= 1) v += __shfl_xor(v, m, 64);
        if (lane == 0) sm[SC + lt] = v + sm[BV1];
    }
    __syncthreads();

    if (tid < NL) {
        float mx = -1e30f;
        for (int t = 0; t < NT; ++t) mx = fmaxf(mx, sm[SC + tid * NT + t]);
        float sum = 0.0f;
        for (int t = 0; t < NT; ++t) {
            float e = expf(sm[SC + tid * NT + t] - mx);
            sm[SC + tid * NT + t] = e;
            sum += e;
        }
        float inv = 1.0f / sum;
        for (int t = 0; t < NT; ++t) sm[SC + tid * NT + t] *= inv;
    }
    __syncthreads();

    {
        float sv = 0.0f;
        #pragma unroll
        for (int t = 0; t < NT; ++t)
            sv += sm[SC + lq * NT + t] * sm[FULLO + (lq * NT + t) * NH + hh];
        sm[CA + tid] = sv;
    }
    __syncthreads();

    if (tid < NG) {
        float bsum = bih[(size_t)s * NG + tid] + bhh[(size_t)s * NG + tid];
        float d[NL];
        #pragma unroll
        for (int l = 0; l < NL; ++l) d[l] = bsum;
        for (int k = 0; k < NH; ++k) {
            float wk = Wih[((size_t)s * NH + k) * NG + tid];
            #pragma unroll
            for (int l = 0; l < NL; ++l)
                d[l] += sm[CA + l * NH + k] * wk;
        }
        #pragma unroll
        for (int l = 0; l < NL; ++l)
            sm[GATES + l * NG + tid] = d[l];
    }
    __syncthreads();
    {
        float gi = sm[GATES + lq * NG + hh];
        float gg = sm[GATES + lq * NG + 128 + hh];
        float go = sm[GATES + lq * NG + 192 + hh];
        float cd = sigf(gi) * tanhf(gg);
        sm[TQ + tid] = sigf(go) * tanhf(cd);
    }
    __syncthreads();

    {
        float v = sm[B0 + lane] + sm[B1 + lane];
        for (int k4 = 0; k4 < NH; k4 += 4) {
            float4 hv = *(const float4*)&sm[TQ + lq * NH + k4];
            v += hv.x * (sm[W1OFF + (k4 + 0) * NH + lane] + sm[W2OFF + (k4 + 0) * NH + lane])
               + hv.y * (sm[W1OFF + (k4 + 1) * NH + lane] + sm[W2OFF + (k4 + 1) * NH + lane])
               + hv.z * (sm[W1OFF + (k4 + 2) * NH + lane] + sm[W2OFF + (k4 + 2) * NH + lane])
               + hv.w * (sm[W1OFF + (k4 + 3) * NH + lane] + sm[W2OFF + (k4 + 3) * NH + lane]);
        }
        v = tanhf(v) * sm[BVV + lane];
        #pragma unroll
        for (int m = 32; m > 0; m >>= 1) v += __shfl_xor(v, m, 64);
        if (lane == 0) sm[SC + lq] = v + sm[BV1];
    }
    __syncthreads();
    if (tid == 0) {
        float mx = -1e30f;
        for (int l = 0; l < NL; ++l) mx = fmaxf(mx, sm[SC + l]);
        float sum = 0.0f;
        for (int l = 0; l < NL; ++l) {
            float e = expf(sm[SC + l] - mx);
            sm[SC + l] = e;
            sum += e;
        }
        float inv = 1.0f / sum;
        for (int l = 0; l < NL; ++l) sm[SC + l] *= inv;
    }
    __syncthreads();

    if (tid < NH) {
        float fv = 0.0f;
        #pragma unroll
        for (int l = 0; l < NL; ++l)
            fv += sm[SC + l] * sm[TQ + l * NH + tid];
        fv *= lin_w[tid];
        #pragma unroll
        for (int m = 32; m > 0; m >>= 1) fv += __shfl_xor(fv, m, 64);
        if (tid == 0) {
            float val = fv + lin_b[0];
            out[s] = val > 0.0f ? val : 0.01f * val;
        }
    }
}

extern "C" void kernel_launch(void* const* d_in, const int* in_sizes, int n_in,
                              void* d_out, int out_size, void* d_ws, size_t ws_size,
                              hipStream_t stream) {
    (void)in_sizes; (void)n_in; (void)out_size; (void)ws_size;
    const float* x     = (const float*)d_in[0];
    const float* ti    = (const float*)d_in[1];
    const float* Wall  = (const float*)d_in[2];
    const float* bWall = (const float*)d_in[3];
    const float* Uall  = (const float*)d_in[4];
    const float* bUall = (const float*)d_in[5];
    const float* Wd    = (const float*)d_in[6];
    const float* bWd   = (const float*)d_in[7];
    const float* W1    = (const float*)d_in[8];
    const float* b1    = (const float*)d_in[9];
    const float* W2    = (const float*)d_in[10];
    const float* b2    = (const float*)d_in[11];
    const float* V     = (const float*)d_in[12];
    const float* bV    = (const float*)d_in[13];
    const float* Wih   = (const float*)d_in[14];
    const float* bih   = (const float*)d_in[16];
    const float* bhh   = (const float*)d_in[17];
    const float* lin_w = (const float*)d_in[18];
    const float* lin_b = (const float*)d_in[19];
    float* out = (float*)d_out;
    float* u = (float*)d_ws;   // [S][T][L][NG] = 52.4 MB

    k_gemm_u<<<NS, 512, 0, stream>>>(x, Uall, bUall, u);
    k_stock<<<NS, 320, 0, stream>>>(u, ti, Wall, bWall, Wd, bWd, W1, b1, W2, b2,
                                    V, bV, Wih, bih, bhh, lin_w, lin_b, out);
}

// Round 5
// 879.548 us; speedup vs baseline: 1.1281x; 1.1281x over previous
//
#include <hip/hip_runtime.h>
#include <cstddef>

#define NS 512
#define NL 5
#define NT 20
#define NE 768
#define NH 64
#define NG 256   // 4*H

__device__ __forceinline__ float sigf(float x) { return 1.0f / (1.0f + expf(-x)); }
__device__ __forceinline__ float bcast(float v, int k) {
    return __int_as_float(__builtin_amdgcn_readlane(__float_as_int(v), k));
}

typedef __attribute__((ext_vector_type(8))) short short8v;   // 8 bf16 = 4 VGPR
typedef __attribute__((ext_vector_type(4))) float f32x4;

// round-to-nearest-ish fp32 -> bf16 split: x ~= hi + lo, residual ~2^-18 |x|
__device__ __forceinline__ void split_bf16(float x, unsigned short& hi, unsigned short& lo) {
    unsigned int bx = __float_as_uint(x);
    unsigned int h = (bx + 0x8000u) >> 16;
    hi = (unsigned short)h;
    float r = x - __uint_as_float(h << 16);
    lo = (unsigned short)((__float_as_uint(r) + 0x8000u) >> 16);
}

// ---------------------------------------------------------------------------
// Kernel 1 (v4, reverted verbatim: measured-good ~194us; v5's 128-VGPR cap +
// A-frag reload regressed it to ~244us)
// ---------------------------------------------------------------------------
__global__ __launch_bounds__(512, 2) void k_gemm_u(
    const float* __restrict__ x, const float* __restrict__ U,
    const float* __restrict__ bU, float* __restrict__ u)
{
    __shared__ unsigned short Af[8 * 2 * 64 * 8];    // [mtile][hl][lane][8] = 16 KB
    __shared__ unsigned short Bf[16 * 2 * 64 * 8];   // [ntile][hl][lane][8] = 32 KB
    const int s = blockIdx.x;
    const int tid = threadIdx.x;
    const int wave = tid >> 6, lane = tid & 63;
    const int wm = wave & 1, wn = wave >> 1;
    const float* xg = x + (size_t)s * (NL * NT * NE);
    const float* Ug = U + (size_t)s * (NE * NG);

    f32x4 acc[4][4] = {};

    const int arow = tid >> 2, ab = tid & 3;
    const unsigned int a_off0 = (((unsigned)(arow >> 4) * 2 + 0) * 64 + ((arow & 15) + 16 * ab)) * 8;
    const unsigned int a_off1 = a_off0 + 64 * 8;     // hl=1
    const int bcol = tid & 255, bq1 = tid >> 8;
    const unsigned int b_base = (unsigned)(bcol >> 4) * 2 * 64 * 8;
    const unsigned int b_off1h = b_base + ((bcol & 15) + 16 * bq1) * 8;
    const unsigned int b_off1l = b_off1h + 64 * 8;
    const unsigned int b_off2h = b_base + ((bcol & 15) + 16 * (bq1 + 2)) * 8;
    const unsigned int b_off2l = b_off2h + 64 * 8;

    float av[8], bv1[8], bv2[8];
    {
        const float* pa = xg + (size_t)arow * NE + ab * 8;
        if (arow < 100) {
            float4 q0 = *(const float4*)pa, q1 = *(const float4*)(pa + 4);
            av[0]=q0.x; av[1]=q0.y; av[2]=q0.z; av[3]=q0.w;
            av[4]=q1.x; av[5]=q1.y; av[6]=q1.z; av[7]=q1.w;
        } else {
            #pragma unroll
            for (int j = 0; j < 8; ++j) av[j] = 0.0f;
        }
        const float* pb = Ug + bcol;
        #pragma unroll
        for (int j = 0; j < 8; ++j) {
            bv1[j] = pb[(size_t)(8 * bq1 + j) * NG];
            bv2[j] = pb[(size_t)(8 * bq1 + 16 + j) * NG];
        }
    }

    for (int st = 0; st < 24; ++st) {
        {
            unsigned short h[8], l[8];
            #pragma unroll
            for (int j = 0; j < 8; ++j) split_bf16(av[j], h[j], l[j]);
            uint4 ph, pl;
            ph.x = h[0] | (h[1] << 16); ph.y = h[2] | (h[3] << 16);
            ph.z = h[4] | (h[5] << 16); ph.w = h[6] | (h[7] << 16);
            pl.x = l[0] | (l[1] << 16); pl.y = l[2] | (l[3] << 16);
            pl.z = l[4] | (l[5] << 16); pl.w = l[6] | (l[7] << 16);
            *(uint4*)&Af[a_off0] = ph;
            *(uint4*)&Af[a_off1] = pl;
            #pragma unroll
            for (int j = 0; j < 8; ++j) split_bf16(bv1[j], h[j], l[j]);
            ph.x = h[0] | (h[1] << 16); ph.y = h[2] | (h[3] << 16);
            ph.z = h[4] | (h[5] << 16); ph.w = h[6] | (h[7] << 16);
            pl.x = l[0] | (l[1] << 16); pl.y = l[2] | (l[3] << 16);
            pl.z = l[4] | (l[5] << 16); pl.w = l[6] | (l[7] << 16);
            *(uint4*)&Bf[b_off1h] = ph;
            *(uint4*)&Bf[b_off1l] = pl;
            #pragma unroll
            for (int j = 0; j < 8; ++j) split_bf16(bv2[j], h[j], l[j]);
            ph.x = h[0] | (h[1] << 16); ph.y = h[2] | (h[3] << 16);
            ph.z = h[4] | (h[5] << 16); ph.w = h[6] | (h[7] << 16);
            pl.x = l[0] | (l[1] << 16); pl.y = l[2] | (l[3] << 16);
            pl.z = l[4] | (l[5] << 16); pl.w = l[6] | (l[7] << 16);
            *(uint4*)&Bf[b_off2h] = ph;
            *(uint4*)&Bf[b_off2l] = pl;
        }
        __syncthreads();

        if (st + 1 < 24) {
            const int k0 = (st + 1) * 32;
            const float* pa = xg + (size_t)arow * NE + k0 + ab * 8;
            if (arow < 100) {
                float4 q0 = *(const float4*)pa, q1 = *(const float4*)(pa + 4);
                av[0]=q0.x; av[1]=q0.y; av[2]=q0.z; av[3]=q0.w;
                av[4]=q1.x; av[5]=q1.y; av[6]=q1.z; av[7]=q1.w;
            } else {
                #pragma unroll
                for (int j = 0; j < 8; ++j) av[j] = 0.0f;
            }
            const float* pb = Ug + (size_t)k0 * NG + bcol;
            #pragma unroll
            for (int j = 0; j < 8; ++j) {
                bv1[j] = pb[(size_t)(8 * bq1 + j) * NG];
                bv2[j] = pb[(size_t)(8 * bq1 + 16 + j) * NG];
            }
        }

        short8v ah[4], al[4];
        #pragma unroll
        for (int mi = 0; mi < 4; ++mi) {
            const unsigned int mt = wm * 4 + mi;
            ah[mi] = *(const short8v*)&Af[(mt * 2 + 0) * 512 + lane * 8];
            al[mi] = *(const short8v*)&Af[(mt * 2 + 1) * 512 + lane * 8];
        }
        #pragma unroll
        for (int ni = 0; ni < 4; ++ni) {
            const unsigned int nt = wn * 4 + ni;
            short8v bh = *(const short8v*)&Bf[(nt * 2 + 0) * 512 + lane * 8];
            short8v bl = *(const short8v*)&Bf[(nt * 2 + 1) * 512 + lane * 8];
            #pragma unroll
            for (int mi = 0; mi < 4; ++mi) {
                acc[mi][ni] = __builtin_amdgcn_mfma_f32_16x16x32_bf16(ah[mi], bh, acc[mi][ni], 0, 0, 0);
                acc[mi][ni] = __builtin_amdgcn_mfma_f32_16x16x32_bf16(ah[mi], bl, acc[mi][ni], 0, 0, 0);
                acc[mi][ni] = __builtin_amdgcn_mfma_f32_16x16x32_bf16(al[mi], bh, acc[mi][ni], 0, 0, 0);
            }
        }
        __syncthreads();
    }

    const int c_sub = 4 * (lane >> 4);
    #pragma unroll
    for (int ni = 0; ni < 4; ++ni) {
        const int gcol = wn * 64 + ni * 16 + (lane & 15);
        const float bb = bU[(size_t)s * NG + gcol];
        #pragma unroll
        for (int mi = 0; mi < 4; ++mi) {
            const int grow0 = wm * 64 + mi * 16 + c_sub;
            #pragma unroll
            for (int r = 0; r < 4; ++r) {
                const int grow = grow0 + r;
                if (grow < 100) {
                    const int ld = grow / 20, td = grow % 20;
                    u[(((size_t)s * NT + td) * NL + ld) * NG + gcol] = acc[mi][ni][r] + bb;
                }
            }
        }
    }
}

// ---------------------------------------------------------------------------
// Kernel 2a: TimeLSTM recurrence only. LDS 23.2 KB + VGPR<=128 => ~4 blocks/CU
// (was 1 block/CU at 67.3 KB): 512 blocks co-resident, latency finally hidden.
// Outputs reuse dead slots of u (gate-inputs are dead once prefetched):
//   o_t    -> u[s][t][l][0..63]    (f-gate slot of step t)
//   h_fin  -> u[s][0][l][64..127]  (i-gate slot of step 0)
// ---------------------------------------------------------------------------
#define R_WD    0        // 4096 fl
#define R_GATES 4096     // 1280
#define R_HS    5376     // 320
#define R_TS    5696     // 100
#define R_TOT   5796     // 23184 B

__global__ __launch_bounds__(320, 4) void k_recur(
    float* __restrict__ u, const float* __restrict__ ti,
    const float* __restrict__ Wall, const float* __restrict__ bWall,
    const float* __restrict__ Wd, const float* __restrict__ bWd)
{
    __shared__ float sm[R_TOT];
    const int s = blockIdx.x;
    const int tid = threadIdx.x;
    const int lq = tid >> 6, hh = tid & 63;
    const int lane = hh;
    float* ug = u + (size_t)s * NT * NL * NG;

    for (int i = tid; i < 1024; i += 320)
        *(float4*)&sm[R_WD + i * 4] = *(const float4*)(Wd + (size_t)s * 4096 + i * 4);
    if (tid < NL * NT) sm[R_TS + tid] = ti[(size_t)s * NL * NT + tid];
    sm[R_HS + tid] = 0.0f;
    const float bwd_r = bWd[(size_t)s * NH + hh];
    float c_reg = 0.0f;
    float wall_r[NH];
    float bwall_r = 0.0f, uc[NL];
    if (tid < NG) {
        bwall_r = bWall[(size_t)s * NG + tid];
        const float* wp = Wall + (size_t)s * (NH * NG) + tid;
        #pragma unroll
        for (int k = 0; k < NH; ++k) wall_r[k] = wp[(size_t)k * NG];
        #pragma unroll
        for (int l = 0; l < NL; ++l) uc[l] = ug[(size_t)l * NG + tid];
    }
    __syncthreads();

    for (int t = 0; t < NT; ++t) {
        float un[NL];
        if (tid < NG) {
            if (t + 1 < NT) {
                #pragma unroll
                for (int l = 0; l < NL; ++l)
                    un[l] = ug[(size_t)((t + 1) * NL + l) * NG + tid];
            } else {
                #pragma unroll
                for (int l = 0; l < NL; ++l) un[l] = 0.0f;
            }
            float hreg[NL];
            #pragma unroll
            for (int l = 0; l < NL; ++l) hreg[l] = sm[R_HS + l * NH + lane];
            float gv[NL];
            #pragma unroll
            for (int l = 0; l < NL; ++l) gv[l] = bwall_r + uc[l];
            #pragma unroll
            for (int k = 0; k < NH; ++k) {
                float w = wall_r[k];
                #pragma unroll
                for (int l = 0; l < NL; ++l)
                    gv[l] += bcast(hreg[l], k) * w;
            }
            #pragma unroll
            for (int l = 0; l < NL; ++l)
                sm[R_GATES + l * NG + tid] = sigf(gv[l]);
        }
        float ssum = bwd_r;
        #pragma unroll
        for (int k = 0; k < NH; ++k)
            ssum += bcast(c_reg, k) * sm[R_WD + k * NH + hh];
        float cs1 = tanhf(ssum);
        float ca = c_reg - cs1 + cs1 * sm[R_TS + lq * NT + t];
        __syncthreads();
        {
            float f  = sm[R_GATES + lq * NG + hh];
            float ii = sm[R_GATES + lq * NG + 64 + hh];
            float oo = sm[R_GATES + lq * NG + 128 + hh];
            float ct = sm[R_GATES + lq * NG + 192 + hh];
            float cn = f * ca + ii * ct;
            c_reg = cn;
            sm[R_HS + tid] = oo * tanhf(cn);
            ug[(size_t)(t * NL + lq) * NG + hh] = oo;       // o_t -> dead f-slot
        }
        __syncthreads();
        if (tid < NG) {
            #pragma unroll
            for (int l = 0; l < NL; ++l) uc[l] = un[l];
        }
    }
    // h_fin -> dead i-slot of t=0 (own-written value, no barrier needed)
    ug[(size_t)(0 * NL + lq) * NG + 64 + hh] = sm[R_HS + tid];
}

// ---------------------------------------------------------------------------
// Kernel 2b: attention + day LSTM + head (parallel phase). Stages FULLO/h_fin
// back from u. LDS packed to 63.4 KB (<64): day-gates alias dead FULLO.
// ---------------------------------------------------------------------------
#define P_W1    0        // 4096
#define P_W2    4096     // 4096
#define P_FULLO 8192     // 6400; aliased by day-GATES after text_vec
#define P_HS    14592    // 320
#define P_TQ    14912    // 320: q, later hd
#define P_CA    15232    // 320: text_vec
#define P_SC    15552    // 100
#define P_B0    15652    // 64
#define P_B1    15716    // 64
#define P_BVV   15780    // 64
#define P_BV1   15844    // 1
#define P_TOT   15848    // 63392 B

__global__ __launch_bounds__(320, 2) void k_post(
    const float* __restrict__ u,
    const float* __restrict__ W1, const float* __restrict__ b1,
    const float* __restrict__ W2, const float* __restrict__ b2,
    const float* __restrict__ V, const float* __restrict__ bV,
    const float* __restrict__ Wih, const float* __restrict__ bih,
    const float* __restrict__ bhh, const float* __restrict__ lin_w,
    const float* __restrict__ lin_b, float* __restrict__ out)
{
    __shared__ float sm[P_TOT];
    const int s = blockIdx.x;
    const int tid = threadIdx.x;
    const int lq = tid >> 6, hh = tid & 63;
    const int lane = hh;
    const float* ug = u + (size_t)s * NT * NL * NG;

    for (int i = tid; i < 1024; i += 320)
        *(float4*)&sm[P_W1 + i * 4] = *(const float4*)(W1 + (size_t)s * 4096 + i * 4);
    for (int i = tid; i < 1024; i += 320)
        *(float4*)&sm[P_W2 + i * 4] = *(const float4*)(W2 + (size_t)s * 4096 + i * 4);
    // FULLO[l][t][h] <- u[s][t][l][0..63]
    for (int i = tid; i < 1600; i += 320) {
        const int idx = i >> 4;            // l*20+t
        const int l = idx / NT, t = idx % NT;
        const int k4 = (i & 15) * 4;
        *(float4*)&sm[P_FULLO + idx * NH + k4] =
            *(const float4*)(ug + (size_t)(t * NL + l) * NG + k4);
    }
    // h_fin <- u[s][0][l][64..127]
    sm[P_HS + tid] = ug[(size_t)(0 * NL + lq) * NG + 64 + hh];
    if (tid < NH) {
        sm[P_B0 + tid]  = b1[(size_t)s * NH + tid];
        sm[P_B1 + tid]  = b2[(size_t)s * NH + tid];
        sm[P_BVV + tid] = V[(size_t)s * NH + tid];
    }
    if (tid == 0) sm[P_BV1] = bV[s];
    __syncthreads();

    // q = h_fin @ W1 + b1
    {
        float qv = sm[P_B0 + hh];
        for (int k4 = 0; k4 < NH; k4 += 4) {
            float4 hv = *(const float4*)&sm[P_HS + lq * NH + k4];
            qv += hv.x * sm[P_W1 + (k4 + 0) * NH + hh]
                + hv.y * sm[P_W1 + (k4 + 1) * NH + hh]
                + hv.z * sm[P_W1 + (k4 + 2) * NH + hh]
                + hv.w * sm[P_W1 + (k4 + 3) * NH + hh];
        }
        sm[P_TQ + tid] = qv;
    }
    __syncthreads();

    // scores
    for (int lt = lq; lt < NL * NT; lt += 5) {
        int l = lt / NT;
        float v = sm[P_TQ + l * NH + lane] + sm[P_B1 + lane];
        for (int k4 = 0; k4 < NH; k4 += 4) {
            float4 fv = *(const float4*)&sm[P_FULLO + lt * NH + k4];
            v += fv.x * sm[P_W2 + (k4 + 0) * NH + lane]
               + fv.y * sm[P_W2 + (k4 + 1) * NH + lane]
               + fv.z * sm[P_W2 + (k4 + 2) * NH + lane]
               + fv.w * sm[P_W2 + (k4 + 3) * NH + lane];
        }
        v = tanhf(v) * sm[P_BVV + lane];
        #pragma unroll
        for (int m = 32; m > 0; m >>= 1) v += __shfl_xor(v, m, 64);
        if (lane == 0) sm[P_SC + lt] = v + sm[P_BV1];
    }
    __syncthreads();

    // softmax over t per l
    if (tid < NL) {
        float mx = -1e30f;
        for (int t = 0; t < NT; ++t) mx = fmaxf(mx, sm[P_SC + tid * NT + t]);
        float sum = 0.0f;
        for (int t = 0; t < NT; ++t) {
            float e = expf(sm[P_SC + tid * NT + t] - mx);
            sm[P_SC + tid * NT + t] = e;
            sum += e;
        }
        float inv = 1.0f / sum;
        for (int t = 0; t < NT; ++t) sm[P_SC + tid * NT + t] *= inv;
    }
    __syncthreads();

    // text_vec -> CA
    {
        float sv = 0.0f;
        #pragma unroll
        for (int t = 0; t < NT; ++t)
            sv += sm[P_SC + lq * NT + t] * sm[P_FULLO + (lq * NT + t) * NH + hh];
        sm[P_CA + tid] = sv;
    }
    __syncthreads();

    // day LSTM: gates alias dead FULLO region
    if (tid < NG) {
        float bsum = bih[(size_t)s * NG + tid] + bhh[(size_t)s * NG + tid];
        float d[NL];
        #pragma unroll
        for (int l = 0; l < NL; ++l) d[l] = bsum;
        for (int k = 0; k < NH; ++k) {
            float wk = Wih[((size_t)s * NH + k) * NG + tid];
            #pragma unroll
            for (int l = 0; l < NL; ++l)
                d[l] += sm[P_CA + l * NH + k] * wk;
        }
        #pragma unroll
        for (int l = 0; l < NL; ++l)
            sm[P_FULLO + l * NG + tid] = d[l];
    }
    __syncthreads();
    {
        float gi = sm[P_FULLO + lq * NG + hh];
        float gg = sm[P_FULLO + lq * NG + 128 + hh];
        float go = sm[P_FULLO + lq * NG + 192 + hh];
        float cd = sigf(gi) * tanhf(gg);
        sm[P_TQ + tid] = sigf(go) * tanhf(cd);   // hd (q dead)
    }
    __syncthreads();

    // day attention
    {
        float v = sm[P_B0 + lane] + sm[P_B1 + lane];
        for (int k4 = 0; k4 < NH; k4 += 4) {
            float4 hv = *(const float4*)&sm[P_TQ + lq * NH + k4];
            v += hv.x * (sm[P_W1 + (k4 + 0) * NH + lane] + sm[P_W2 + (k4 + 0) * NH + lane])
               + hv.y * (sm[P_W1 + (k4 + 1) * NH + lane] + sm[P_W2 + (k4 + 1) * NH + lane])
               + hv.z * (sm[P_W1 + (k4 + 2) * NH + lane] + sm[P_W2 + (k4 + 2) * NH + lane])
               + hv.w * (sm[P_W1 + (k4 + 3) * NH + lane] + sm[P_W2 + (k4 + 3) * NH + lane]);
        }
        v = tanhf(v) * sm[P_BVV + lane];
        #pragma unroll
        for (int m = 32; m > 0; m >>= 1) v += __shfl_xor(v, m, 64);
        if (lane == 0) sm[P_SC + lq] = v + sm[P_BV1];
    }
    __syncthreads();
    if (tid == 0) {
        float mx = -1e30f;
        for (int l = 0; l < NL; ++l) mx = fmaxf(mx, sm[P_SC + l]);
        float sum = 0.0f;
        for (int l = 0; l < NL; ++l) {
            float e = expf(sm[P_SC + l] - mx);
            sm[P_SC + l] = e;
            sum += e;
        }
        float inv = 1.0f / sum;
        for (int l = 0; l < NL; ++l) sm[P_SC + l] *= inv;
    }
    __syncthreads();

    if (tid < NH) {
        float fv = 0.0f;
        #pragma unroll
        for (int l = 0; l < NL; ++l)
            fv += sm[P_SC + l] * sm[P_TQ + l * NH + tid];
        fv *= lin_w[tid];
        #pragma unroll
        for (int m = 32; m > 0; m >>= 1) fv += __shfl_xor(fv, m, 64);
        if (tid == 0) {
            float val = fv + lin_b[0];
            out[s] = val > 0.0f ? val : 0.01f * val;
        }
    }
}

extern "C" void kernel_launch(void* const* d_in, const int* in_sizes, int n_in,
                              void* d_out, int out_size, void* d_ws, size_t ws_size,
                              hipStream_t stream) {
    (void)in_sizes; (void)n_in; (void)out_size; (void)ws_size;
    const float* x     = (const float*)d_in[0];
    const float* ti    = (const float*)d_in[1];
    const float* Wall  = (const float*)d_in[2];
    const float* bWall = (const float*)d_in[3];
    const float* Uall  = (const float*)d_in[4];
    const float* bUall = (const float*)d_in[5];
    const float* Wd    = (const float*)d_in[6];
    const float* bWd   = (const float*)d_in[7];
    const float* W1    = (const float*)d_in[8];
    const float* b1    = (const float*)d_in[9];
    const float* W2    = (const float*)d_in[10];
    const float* b2    = (const float*)d_in[11];
    const float* V     = (const float*)d_in[12];
    const float* bV    = (const float*)d_in[13];
    const float* Wih   = (const float*)d_in[14];
    const float* bih   = (const float*)d_in[16];
    const float* bhh   = (const float*)d_in[17];
    const float* lin_w = (const float*)d_in[18];
    const float* lin_b = (const float*)d_in[19];
    float* out = (float*)d_out;
    float* u = (float*)d_ws;   // [S][T][L][NG] = 52.4 MB

    k_gemm_u<<<NS, 512, 0, stream>>>(x, Uall, bUall, u);
    k_recur<<<NS, 320, 0, stream>>>(u, ti, Wall, bWall, Wd, bWd);
    k_post<<<NS, 320, 0, stream>>>(u, W1, b1, W2, b2, V, bV,
                                   Wih, bih, bhh, lin_w, lin_b, out);
}

// Round 6
// 873.848 us; speedup vs baseline: 1.1355x; 1.0065x over previous
//
#include <hip/hip_runtime.h>
#include <cstddef>

#define NS 512
#define NL 5
#define NT 20
#define NE 768
#define NH 64
#define NG 256   // 4*H

__device__ __forceinline__ float sigf(float x) { return 1.0f / (1.0f + expf(-x)); }
__device__ __forceinline__ float bcast(float v, int k) {
    return __int_as_float(__builtin_amdgcn_readlane(__float_as_int(v), k));
}

typedef __attribute__((ext_vector_type(8))) short short8v;   // 8 bf16 = 4 VGPR
typedef __attribute__((ext_vector_type(4))) float f32x4;

// round-to-nearest-ish fp32 -> bf16 split: x ~= hi + lo, residual ~2^-18 |x|
__device__ __forceinline__ void split_bf16(float x, unsigned short& hi, unsigned short& lo) {
    unsigned int bx = __float_as_uint(x);
    unsigned int h = (bx + 0x8000u) >> 16;
    hi = (unsigned short)h;
    float r = x - __uint_as_float(h << 16);
    lo = (unsigned short)((__float_as_uint(r) + 0x8000u) >> 16);
}

// ---------------------------------------------------------------------------
// Kernel 1 v6 = v4 body + 2-deep register prefetch (unroll-2, buffers A/B).
// v4's 1-deep prefetch left a dead HBM window every K-step (stage + latency
// ramp with all 8 waves sync-stalled on the same vmcnt; 1 block/CU => no other
// block to cover). With 2-deep, loads for step st+1 are already in flight
// while staging st => HBM continuously fed. Arithmetic order identical to v4.
// ---------------------------------------------------------------------------
__device__ __forceinline__ void kg_load(
    const float* __restrict__ xg, const float* __restrict__ Ug,
    int arow, int ab, int bcol, int bq1, int k0,
    float av[8], float bv1[8], float bv2[8])
{
    const float* pa = xg + (size_t)arow * NE + k0 + ab * 8;
    if (arow < 100) {
        float4 q0 = *(const float4*)pa, q1 = *(const float4*)(pa + 4);
        av[0]=q0.x; av[1]=q0.y; av[2]=q0.z; av[3]=q0.w;
        av[4]=q1.x; av[5]=q1.y; av[6]=q1.z; av[7]=q1.w;
    } else {
        #pragma unroll
        for (int j = 0; j < 8; ++j) av[j] = 0.0f;
    }
    const float* pb = Ug + (size_t)k0 * NG + bcol;
    #pragma unroll
    for (int j = 0; j < 8; ++j) {
        bv1[j] = pb[(size_t)(8 * bq1 + j) * NG];
        bv2[j] = pb[(size_t)(8 * bq1 + 16 + j) * NG];
    }
}

__device__ __forceinline__ void kg_stage(
    const float av[8], const float bv1[8], const float bv2[8],
    unsigned short* __restrict__ Af, unsigned short* __restrict__ Bf,
    unsigned a_off0, unsigned a_off1,
    unsigned b_off1h, unsigned b_off1l, unsigned b_off2h, unsigned b_off2l)
{
    unsigned short h[8], l[8];
    uint4 ph, pl;
    #pragma unroll
    for (int j = 0; j < 8; ++j) split_bf16(av[j], h[j], l[j]);
    ph.x = h[0] | (h[1] << 16); ph.y = h[2] | (h[3] << 16);
    ph.z = h[4] | (h[5] << 16); ph.w = h[6] | (h[7] << 16);
    pl.x = l[0] | (l[1] << 16); pl.y = l[2] | (l[3] << 16);
    pl.z = l[4] | (l[5] << 16); pl.w = l[6] | (l[7] << 16);
    *(uint4*)&Af[a_off0] = ph;
    *(uint4*)&Af[a_off1] = pl;
    #pragma unroll
    for (int j = 0; j < 8; ++j) split_bf16(bv1[j], h[j], l[j]);
    ph.x = h[0] | (h[1] << 16); ph.y = h[2] | (h[3] << 16);
    ph.z = h[4] | (h[5] << 16); ph.w = h[6] | (h[7] << 16);
    pl.x = l[0] | (l[1] << 16); pl.y = l[2] | (l[3] << 16);
    pl.z = l[4] | (l[5] << 16); pl.w = l[6] | (l[7] << 16);
    *(uint4*)&Bf[b_off1h] = ph;
    *(uint4*)&Bf[b_off1l] = pl;
    #pragma unroll
    for (int j = 0; j < 8; ++j) split_bf16(bv2[j], h[j], l[j]);
    ph.x = h[0] | (h[1] << 16); ph.y = h[2] | (h[3] << 16);
    ph.z = h[4] | (h[5] << 16); ph.w = h[6] | (h[7] << 16);
    pl.x = l[0] | (l[1] << 16); pl.y = l[2] | (l[3] << 16);
    pl.z = l[4] | (l[5] << 16); pl.w = l[6] | (l[7] << 16);
    *(uint4*)&Bf[b_off2h] = ph;
    *(uint4*)&Bf[b_off2l] = pl;
}

__device__ __forceinline__ void kg_mfma(
    f32x4 (&acc)[4][4], const unsigned short* __restrict__ Af,
    const unsigned short* __restrict__ Bf, int wm, int wn, int lane)
{
    short8v ah[4], al[4];
    #pragma unroll
    for (int mi = 0; mi < 4; ++mi) {
        const unsigned int mt = wm * 4 + mi;
        ah[mi] = *(const short8v*)&Af[(mt * 2 + 0) * 512 + lane * 8];
        al[mi] = *(const short8v*)&Af[(mt * 2 + 1) * 512 + lane * 8];
    }
    #pragma unroll
    for (int ni = 0; ni < 4; ++ni) {
        const unsigned int nt = wn * 4 + ni;
        short8v bh = *(const short8v*)&Bf[(nt * 2 + 0) * 512 + lane * 8];
        short8v bl = *(const short8v*)&Bf[(nt * 2 + 1) * 512 + lane * 8];
        #pragma unroll
        for (int mi = 0; mi < 4; ++mi) {
            acc[mi][ni] = __builtin_amdgcn_mfma_f32_16x16x32_bf16(ah[mi], bh, acc[mi][ni], 0, 0, 0);
            acc[mi][ni] = __builtin_amdgcn_mfma_f32_16x16x32_bf16(ah[mi], bl, acc[mi][ni], 0, 0, 0);
            acc[mi][ni] = __builtin_amdgcn_mfma_f32_16x16x32_bf16(al[mi], bh, acc[mi][ni], 0, 0, 0);
        }
    }
}

__global__ __launch_bounds__(512, 2) void k_gemm_u(
    const float* __restrict__ x, const float* __restrict__ U,
    const float* __restrict__ bU, float* __restrict__ u)
{
    __shared__ unsigned short Af[8 * 2 * 64 * 8];    // 16 KB
    __shared__ unsigned short Bf[16 * 2 * 64 * 8];   // 32 KB
    const int s = blockIdx.x;
    const int tid = threadIdx.x;
    const int wave = tid >> 6, lane = tid & 63;
    const int wm = wave & 1, wn = wave >> 1;
    const float* xg = x + (size_t)s * (NL * NT * NE);
    const float* Ug = U + (size_t)s * (NE * NG);

    f32x4 acc[4][4] = {};

    const int arow = tid >> 2, ab = tid & 3;
    const unsigned int a_off0 = (((unsigned)(arow >> 4) * 2 + 0) * 64 + ((arow & 15) + 16 * ab)) * 8;
    const unsigned int a_off1 = a_off0 + 64 * 8;
    const int bcol = tid & 255, bq1 = tid >> 8;
    const unsigned int b_base = (unsigned)(bcol >> 4) * 2 * 64 * 8;
    const unsigned int b_off1h = b_base + ((bcol & 15) + 16 * bq1) * 8;
    const unsigned int b_off1l = b_off1h + 64 * 8;
    const unsigned int b_off2h = b_base + ((bcol & 15) + 16 * (bq1 + 2)) * 8;
    const unsigned int b_off2l = b_off2h + 64 * 8;

    float avA[8], bv1A[8], bv2A[8];
    float avB[8], bv1B[8], bv2B[8];
    kg_load(xg, Ug, arow, ab, bcol, bq1, 0,  avA, bv1A, bv2A);
    kg_load(xg, Ug, arow, ab, bcol, bq1, 32, avB, bv1B, bv2B);

    for (int st = 0; st < 24; st += 2) {
        // ---- even sub-step: stage buffer A (data for st), reload A for st+2
        kg_stage(avA, bv1A, bv2A, Af, Bf, a_off0, a_off1,
                 b_off1h, b_off1l, b_off2h, b_off2l);
        if (st + 2 < 24)
            kg_load(xg, Ug, arow, ab, bcol, bq1, (st + 2) * 32, avA, bv1A, bv2A);
        __syncthreads();
        kg_mfma(acc, Af, Bf, wm, wn, lane);
        __syncthreads();

        // ---- odd sub-step: stage buffer B (data for st+1), reload B for st+3
        kg_stage(avB, bv1B, bv2B, Af, Bf, a_off0, a_off1,
                 b_off1h, b_off1l, b_off2h, b_off2l);
        if (st + 3 < 24)
            kg_load(xg, Ug, arow, ab, bcol, bq1, (st + 3) * 32, avB, bv1B, bv2B);
        __syncthreads();
        kg_mfma(acc, Af, Bf, wm, wn, lane);
        __syncthreads();
    }

    const int c_sub = 4 * (lane >> 4);
    #pragma unroll
    for (int ni = 0; ni < 4; ++ni) {
        const int gcol = wn * 64 + ni * 16 + (lane & 15);
        const float bb = bU[(size_t)s * NG + gcol];
        #pragma unroll
        for (int mi = 0; mi < 4; ++mi) {
            const int grow0 = wm * 64 + mi * 16 + c_sub;
            #pragma unroll
            for (int r = 0; r < 4; ++r) {
                const int grow = grow0 + r;
                if (grow < 100) {
                    const int ld = grow / 20, td = grow % 20;
                    u[(((size_t)s * NT + td) * NL + ld) * NG + gcol] = acc[mi][ni][r] + bb;
                }
            }
        }
    }
}

// ---------------------------------------------------------------------------
// Kernel 2a (unchanged from round 5): TimeLSTM recurrence, 23.2 KB LDS.
// o_t -> u[s][t][l][0..63] (dead f-slot); h_fin -> u[s][0][l][64..127].
// ---------------------------------------------------------------------------
#define R_WD    0
#define R_GATES 4096
#define R_HS    5376
#define R_TS    5696
#define R_TOT   5796

__global__ __launch_bounds__(320, 4) void k_recur(
    float* __restrict__ u, const float* __restrict__ ti,
    const float* __restrict__ Wall, const float* __restrict__ bWall,
    const float* __restrict__ Wd, const float* __restrict__ bWd)
{
    __shared__ float sm[R_TOT];
    const int s = blockIdx.x;
    const int tid = threadIdx.x;
    const int lq = tid >> 6, hh = tid & 63;
    const int lane = hh;
    float* ug = u + (size_t)s * NT * NL * NG;

    for (int i = tid; i < 1024; i += 320)
        *(float4*)&sm[R_WD + i * 4] = *(const float4*)(Wd + (size_t)s * 4096 + i * 4);
    if (tid < NL * NT) sm[R_TS + tid] = ti[(size_t)s * NL * NT + tid];
    sm[R_HS + tid] = 0.0f;
    const float bwd_r = bWd[(size_t)s * NH + hh];
    float c_reg = 0.0f;
    float wall_r[NH];
    float bwall_r = 0.0f, uc[NL];
    if (tid < NG) {
        bwall_r = bWall[(size_t)s * NG + tid];
        const float* wp = Wall + (size_t)s * (NH * NG) + tid;
        #pragma unroll
        for (int k = 0; k < NH; ++k) wall_r[k] = wp[(size_t)k * NG];
        #pragma unroll
        for (int l = 0; l < NL; ++l) uc[l] = ug[(size_t)l * NG + tid];
    }
    __syncthreads();

    for (int t = 0; t < NT; ++t) {
        float un[NL];
        if (tid < NG) {
            if (t + 1 < NT) {
                #pragma unroll
                for (int l = 0; l < NL; ++l)
                    un[l] = ug[(size_t)((t + 1) * NL + l) * NG + tid];
            } else {
                #pragma unroll
                for (int l = 0; l < NL; ++l) un[l] = 0.0f;
            }
            float hreg[NL];
            #pragma unroll
            for (int l = 0; l < NL; ++l) hreg[l] = sm[R_HS + l * NH + lane];
            float gv[NL];
            #pragma unroll
            for (int l = 0; l < NL; ++l) gv[l] = bwall_r + uc[l];
            #pragma unroll
            for (int k = 0; k < NH; ++k) {
                float w = wall_r[k];
                #pragma unroll
                for (int l = 0; l < NL; ++l)
                    gv[l] += bcast(hreg[l], k) * w;
            }
            #pragma unroll
            for (int l = 0; l < NL; ++l)
                sm[R_GATES + l * NG + tid] = sigf(gv[l]);
        }
        float ssum = bwd_r;
        #pragma unroll
        for (int k = 0; k < NH; ++k)
            ssum += bcast(c_reg, k) * sm[R_WD + k * NH + hh];
        float cs1 = tanhf(ssum);
        float ca = c_reg - cs1 + cs1 * sm[R_TS + lq * NT + t];
        __syncthreads();
        {
            float f  = sm[R_GATES + lq * NG + hh];
            float ii = sm[R_GATES + lq * NG + 64 + hh];
            float oo = sm[R_GATES + lq * NG + 128 + hh];
            float ct = sm[R_GATES + lq * NG + 192 + hh];
            float cn = f * ca + ii * ct;
            c_reg = cn;
            sm[R_HS + tid] = oo * tanhf(cn);
            ug[(size_t)(t * NL + lq) * NG + hh] = oo;       // o_t -> dead f-slot
        }
        __syncthreads();
        if (tid < NG) {
            #pragma unroll
            for (int l = 0; l < NL; ++l) uc[l] = un[l];
        }
    }
    ug[(size_t)(0 * NL + lq) * NG + 64 + hh] = sm[R_HS + tid];
}

// ---------------------------------------------------------------------------
// Kernel 2b (unchanged from round 5): attention + day LSTM + head.
// ---------------------------------------------------------------------------
#define P_W1    0
#define P_W2    4096
#define P_FULLO 8192
#define P_HS    14592
#define P_TQ    14912
#define P_CA    15232
#define P_SC    15552
#define P_B0    15652
#define P_B1    15716
#define P_BVV   15780
#define P_BV1   15844
#define P_TOT   15848

__global__ __launch_bounds__(320, 2) void k_post(
    const float* __restrict__ u,
    const float* __restrict__ W1, const float* __restrict__ b1,
    const float* __restrict__ W2, const float* __restrict__ b2,
    const float* __restrict__ V, const float* __restrict__ bV,
    const float* __restrict__ Wih, const float* __restrict__ bih,
    const float* __restrict__ bhh, const float* __restrict__ lin_w,
    const float* __restrict__ lin_b, float* __restrict__ out)
{
    __shared__ float sm[P_TOT];
    const int s = blockIdx.x;
    const int tid = threadIdx.x;
    const int lq = tid >> 6, hh = tid & 63;
    const int lane = hh;
    const float* ug = u + (size_t)s * NT * NL * NG;

    for (int i = tid; i < 1024; i += 320)
        *(float4*)&sm[P_W1 + i * 4] = *(const float4*)(W1 + (size_t)s * 4096 + i * 4);
    for (int i = tid; i < 1024; i += 320)
        *(float4*)&sm[P_W2 + i * 4] = *(const float4*)(W2 + (size_t)s * 4096 + i * 4);
    for (int i = tid; i < 1600; i += 320) {
        const int idx = i >> 4;
        const int l = idx / NT, t = idx % NT;
        const int k4 = (i & 15) * 4;
        *(float4*)&sm[P_FULLO + idx * NH + k4] =
            *(const float4*)(ug + (size_t)(t * NL + l) * NG + k4);
    }
    sm[P_HS + tid] = ug[(size_t)(0 * NL + lq) * NG + 64 + hh];
    if (tid < NH) {
        sm[P_B0 + tid]  = b1[(size_t)s * NH + tid];
        sm[P_B1 + tid]  = b2[(size_t)s * NH + tid];
        sm[P_BVV + tid] = V[(size_t)s * NH + tid];
    }
    if (tid == 0) sm[P_BV1] = bV[s];
    __syncthreads();

    {
        float qv = sm[P_B0 + hh];
        for (int k4 = 0; k4 < NH; k4 += 4) {
            float4 hv = *(const float4*)&sm[P_HS + lq * NH + k4];
            qv += hv.x * sm[P_W1 + (k4 + 0) * NH + hh]
                + hv.y * sm[P_W1 + (k4 + 1) * NH + hh]
                + hv.z * sm[P_W1 + (k4 + 2) * NH + hh]
                + hv.w * sm[P_W1 + (k4 + 3) * NH + hh];
        }
        sm[P_TQ + tid] = qv;
    }
    __syncthreads();

    for (int lt = lq; lt < NL * NT; lt += 5) {
        int l = lt / NT;
        float v = sm[P_TQ + l * NH + lane] + sm[P_B1 + lane];
        for (int k4 = 0; k4 < NH; k4 += 4) {
            float4 fv = *(const float4*)&sm[P_FULLO + lt * NH + k4];
            v += fv.x * sm[P_W2 + (k4 + 0) * NH + lane]
               + fv.y * sm[P_W2 + (k4 + 1) * NH + lane]
               + fv.z * sm[P_W2 + (k4 + 2) * NH + lane]
               + fv.w * sm[P_W2 + (k4 + 3) * NH + lane];
        }
        v = tanhf(v) * sm[P_BVV + lane];
        #pragma unroll
        for (int m = 32; m > 0; m >>= 1) v += __shfl_xor(v, m, 64);
        if (lane == 0) sm[P_SC + lt] = v + sm[P_BV1];
    }
    __syncthreads();

    if (tid < NL) {
        float mx = -1e30f;
        for (int t = 0; t < NT; ++t) mx = fmaxf(mx, sm[P_SC + tid * NT + t]);
        float sum = 0.0f;
        for (int t = 0; t < NT; ++t) {
            float e = expf(sm[P_SC + tid * NT + t] - mx);
            sm[P_SC + tid * NT + t] = e;
            sum += e;
        }
        float inv = 1.0f / sum;
        for (int t = 0; t < NT; ++t) sm[P_SC + tid * NT + t] *= inv;
    }
    __syncthreads();

    {
        float sv = 0.0f;
        #pragma unroll
        for (int t = 0; t < NT; ++t)
            sv += sm[P_SC + lq * NT + t] * sm[P_FULLO + (lq * NT + t) * NH + hh];
        sm[P_CA + tid] = sv;
    }
    __syncthreads();

    if (tid < NG) {
        float bsum = bih[(size_t)s * NG + tid] + bhh[(size_t)s * NG + tid];
        float d[NL];
        #pragma unroll
        for (int l = 0; l < NL; ++l) d[l] = bsum;
        for (int k = 0; k < NH; ++k) {
            float wk = Wih[((size_t)s * NH + k) * NG + tid];
            #pragma unroll
            for (int l = 0; l < NL; ++l)
                d[l] += sm[P_CA + l * NH + k] * wk;
        }
        #pragma unroll
        for (int l = 0; l < NL; ++l)
            sm[P_FULLO + l * NG + tid] = d[l];
    }
    __syncthreads();
    {
        float gi = sm[P_FULLO + lq * NG + hh];
        float gg = sm[P_FULLO + lq * NG + 128 + hh];
        float go = sm[P_FULLO + lq * NG + 192 + hh];
        float cd = sigf(gi) * tanhf(gg);
        sm[P_TQ + tid] = sigf(go) * tanhf(cd);
    }
    __syncthreads();

    {
        float v = sm[P_B0 + lane] + sm[P_B1 + lane];
        for (int k4 = 0; k4 < NH; k4 += 4) {
            float4 hv = *(const float4*)&sm[P_TQ + lq * NH + k4];
            v += hv.x * (sm[P_W1 + (k4 + 0) * NH + lane] + sm[P_W2 + (k4 + 0) * NH + lane])
               + hv.y * (sm[P_W1 + (k4 + 1) * NH + lane] + sm[P_W2 + (k4 + 1) * NH + lane])
               + hv.z * (sm[P_W1 + (k4 + 2) * NH + lane] + sm[P_W2 + (k4 + 2) * NH + lane])
               + hv.w * (sm[P_W1 + (k4 + 3) * NH + lane] + sm[P_W2 + (k4 + 3) * NH + lane]);
        }
        v = tanhf(v) * sm[P_BVV + lane];
        #pragma unroll
        for (int m = 32; m > 0; m >>= 1) v += __shfl_xor(v, m, 64);
        if (lane == 0) sm[P_SC + lq] = v + sm[P_BV1];
    }
    __syncthreads();
    if (tid == 0) {
        float mx = -1e30f;
        for (int l = 0; l < NL; ++l) mx = fmaxf(mx, sm[P_SC + l]);
        float sum = 0.0f;
        for (int l = 0; l < NL; ++l) {
            float e = expf(sm[P_SC + l] - mx);
            sm[P_SC + l] = e;
            sum += e;
        }
        float inv = 1.0f / sum;
        for (int l = 0; l < NL; ++l) sm[P_SC + l] *= inv;
    }
    __syncthreads();

    if (tid < NH) {
        float fv = 0.0f;
        #pragma unroll
        for (int l = 0; l < NL; ++l)
            fv += sm[P_SC + l] * sm[P_TQ + l * NH + tid];
        fv *= lin_w[tid];
        #pragma unroll
        for (int m = 32; m > 0; m >>= 1) fv += __shfl_xor(fv, m, 64);
        if (tid == 0) {
            float val = fv + lin_b[0];
            out[s] = val > 0.0f ? val : 0.01f * val;
        }
    }
}

extern "C" void kernel_launch(void* const* d_in, const int* in_sizes, int n_in,
                              void* d_out, int out_size, void* d_ws, size_t ws_size,
                              hipStream_t stream) {
    (void)in_sizes; (void)n_in; (void)out_size; (void)ws_size;
    const float* x     = (const float*)d_in[0];
    const float* ti    = (const float*)d_in[1];
    const float* Wall  = (const float*)d_in[2];
    const float* bWall = (const float*)d_in[3];
    const float* Uall  = (const float*)d_in[4];
    const float* bUall = (const float*)d_in[5];
    const float* Wd    = (const float*)d_in[6];
    const float* bWd   = (const float*)d_in[7];
    const float* W1    = (const float*)d_in[8];
    const float* b1    = (const float*)d_in[9];
    const float* W2    = (const float*)d_in[10];
    const float* b2    = (const float*)d_in[11];
    const float* V     = (const float*)d_in[12];
    const float* bV    = (const float*)d_in[13];
    const float* Wih   = (const float*)d_in[14];
    const float* bih   = (const float*)d_in[16];
    const float* bhh   = (const float*)d_in[17];
    const float* lin_w = (const float*)d_in[18];
    const float* lin_b = (const float*)d_in[19];
    float* out = (float*)d_out;
    float* u = (float*)d_ws;   // [S][T][L][NG] = 52.4 MB

    k_gemm_u<<<NS, 512, 0, stream>>>(x, Uall, bUall, u);
    k_recur<<<NS, 320, 0, stream>>>(u, ti, Wall, bWall, Wd, bWd);
    k_post<<<NS, 320, 0, stream>>>(u, W1, b1, W2, b2, V, bV,
                                   Wih, bih, bhh, lin_w, lin_b, out);
}

// Round 8
// 873.102 us; speedup vs baseline: 1.1365x; 1.0009x over previous
//
#include <hip/hip_runtime.h>
#include <cstddef>

#define NS 512
#define NL 5
#define NT 20
#define NE 768
#define NH 64
#define NG 256   // 4*H

__device__ __forceinline__ float sigf(float x) { return 1.0f / (1.0f + expf(-x)); }

typedef __fp16 h16x2 __attribute__((ext_vector_type(2)));
typedef _Float16 f16x8 __attribute__((ext_vector_type(8)));
typedef __attribute__((ext_vector_type(4))) float f32x4;

union PkU { h16x2 h; unsigned u; };

// fp16 2-way split via v_cvt_pkrtz (1 inst / 2 values): x ~= hi + lo with
// residual ~2^-22|x|; 3-term MFMA (hh+hl+lh) then ~2^-23 rel -- better than
// the old bf16 3-term split AND ~2.5x fewer stage-VALU instructions.
__device__ __forceinline__ void split_pk(float a, float b, unsigned& hi, unsigned& lo) {
    PkU H, L;
    H.h = __builtin_amdgcn_cvt_pkrtz(a, b);
    float ra = a - (float)H.h[0];
    float rb = b - (float)H.h[1];
    L.h = __builtin_amdgcn_cvt_pkrtz(ra, rb);
    hi = H.u; lo = L.u;
}

__device__ __forceinline__ void stage8(const float v[8], unsigned short* base, unsigned off) {
    uint4 ph, pl;
    split_pk(v[0], v[1], ph.x, pl.x);
    split_pk(v[2], v[3], ph.y, pl.y);
    split_pk(v[4], v[5], ph.z, pl.z);
    split_pk(v[6], v[7], ph.w, pl.w);
    *(uint4*)&base[off]       = ph;
    *(uint4*)&base[off + 512] = pl;
}

// ---------------------------------------------------------------------------
// Kernel 1 v7: fp16-split MFMA, N-split into 2 blocks/stock (N=128 each).
// Why: v4-v6 were issue-bound inside barrier phases at 1 block/CU (HBM only
// ~50% busy). N=128 halves acc (32 VGPR) -> ~100 VGPR total fits 4 waves/SIMD
// => 2 blocks/CU co-resident: one block's MFMA phase covers the other's
// stage phase. Stage-VALU cut ~2.5x via cvt_pkrtz. LDS 32 KB/block.
// Cost: x read twice (L2/L3 should absorb most; x total 157 MB < 256 MB L3).
// ---------------------------------------------------------------------------
__global__ __launch_bounds__(512, 4) void k_gemm_u(
    const float* __restrict__ x, const float* __restrict__ U,
    const float* __restrict__ bU, float* __restrict__ u)
{
    __shared__ unsigned short Af[8 * 2 * 512];   // [mtile][hl][lane*8] = 16 KB
    __shared__ unsigned short Bf[8 * 2 * 512];   // [ntile][hl][lane*8] = 16 KB
    const int bid = blockIdx.x;
    const int s = bid >> 1, half = bid & 1;
    const int tid = threadIdx.x;
    const int wave = tid >> 6, lane = tid & 63;
    const int wm = wave & 1, wn = wave >> 1;     // wave owns mt wm*4+mi, nt wn*2+ni
    const float* xg = x + (size_t)s * (NL * NT * NE);
    const float* Ug = U + (size_t)s * (NE * NG) + half * 128;

    f32x4 acc[4][2] = {};

    // A staging: thread -> (row, octet): 8 floats x[row][k0+8b..+7]
    const int arow = tid >> 2, ab = tid & 3;
    const unsigned a_off = ((unsigned)(arow >> 4) * 2) * 512 + ((arow & 15) + 16 * ab) * 8;
    // B staging: thread -> (col, k-octet): 8 floats U[k0+8q..+7][col]
    const int bcol = tid & 127, bkq = tid >> 7;
    const unsigned b_off = ((unsigned)(bcol >> 4) * 2) * 512 + ((bcol & 15) + 16 * bkq) * 8;

    float av[8], bv[8];
    {
        const float* pa = xg + (size_t)arow * NE + ab * 8;
        if (arow < 100) {
            float4 q0 = *(const float4*)pa, q1 = *(const float4*)(pa + 4);
            av[0]=q0.x; av[1]=q0.y; av[2]=q0.z; av[3]=q0.w;
            av[4]=q1.x; av[5]=q1.y; av[6]=q1.z; av[7]=q1.w;
        } else {
            #pragma unroll
            for (int j = 0; j < 8; ++j) av[j] = 0.0f;
        }
        #pragma unroll
        for (int j = 0; j < 8; ++j)
            bv[j] = Ug[(size_t)(8 * bkq + j) * NG + bcol];
    }

    for (int st = 0; st < 24; ++st) {
        stage8(av, Af, a_off);
        stage8(bv, Bf, b_off);
        __syncthreads();

        if (st + 1 < 24) {
            const int k0 = (st + 1) * 32;
            const float* pa = xg + (size_t)arow * NE + k0 + ab * 8;
            if (arow < 100) {
                float4 q0 = *(const float4*)pa, q1 = *(const float4*)(pa + 4);
                av[0]=q0.x; av[1]=q0.y; av[2]=q0.z; av[3]=q0.w;
                av[4]=q1.x; av[5]=q1.y; av[6]=q1.z; av[7]=q1.w;
            } else {
                #pragma unroll
                for (int j = 0; j < 8; ++j) av[j] = 0.0f;
            }
            #pragma unroll
            for (int j = 0; j < 8; ++j)
                bv[j] = Ug[(size_t)(k0 + 8 * bkq + j) * NG + bcol];
        }

        f16x8 bh[2], bl[2];
        #pragma unroll
        for (int ni = 0; ni < 2; ++ni) {
            const unsigned nt = wn * 2 + ni;
            bh[ni] = *(const f16x8*)&Bf[(nt * 2 + 0) * 512 + lane * 8];
            bl[ni] = *(const f16x8*)&Bf[(nt * 2 + 1) * 512 + lane * 8];
        }
        #pragma unroll
        for (int mi = 0; mi < 4; ++mi) {
            const unsigned mt = wm * 4 + mi;
            f16x8 ah = *(const f16x8*)&Af[(mt * 2 + 0) * 512 + lane * 8];
            f16x8 al = *(const f16x8*)&Af[(mt * 2 + 1) * 512 + lane * 8];
            #pragma unroll
            for (int ni = 0; ni < 2; ++ni) {
                acc[mi][ni] = __builtin_amdgcn_mfma_f32_16x16x32_f16(ah, bh[ni], acc[mi][ni], 0, 0, 0);
                acc[mi][ni] = __builtin_amdgcn_mfma_f32_16x16x32_f16(ah, bl[ni], acc[mi][ni], 0, 0, 0);
                acc[mi][ni] = __builtin_amdgcn_mfma_f32_16x16x32_f16(al, bh[ni], acc[mi][ni], 0, 0, 0);
            }
        }
        __syncthreads();
    }

    // epilogue (C/D: col=lane&15, row=4*(lane>>4)+r)
    const int c_sub = 4 * (lane >> 4);
    #pragma unroll
    for (int ni = 0; ni < 2; ++ni) {
        const int gcol = half * 128 + (wn * 2 + ni) * 16 + (lane & 15);
        const float bb = bU[(size_t)s * NG + gcol];
        #pragma unroll
        for (int mi = 0; mi < 4; ++mi) {
            const int grow0 = wm * 64 + mi * 16 + c_sub;
            #pragma unroll
            for (int r = 0; r < 4; ++r) {
                const int grow = grow0 + r;
                if (grow < 100) {
                    const int ld = grow / 20, td = grow % 20;
                    u[(((size_t)s * NT + td) * NL + ld) * NG + gcol] = acc[mi][ni][r] + bb;
                }
            }
        }
    }
}

// ---------------------------------------------------------------------------
// Kernel 2a v2: readlane broadcasts removed (SGPR-write->VALU-read hazards,
// all on one pipe). h and c broadcasts are wave-uniform LDS float4 reads
// (conflict-free broadcast, LDS pipe) -- work now split across VALU+LDS
// pipes, overlapping at 2 blocks/CU. Wall stays in VGPRs (no LDS w-reads).
// ---------------------------------------------------------------------------
#define R_WD    0        // 4096
#define R_GATES 4096     // 1280
#define R_HS    5376     // 320
#define R_CS    5696     // 320
#define R_TS    6016     // 100
#define R_TOT   6116     // 24464 B

__global__ __launch_bounds__(320, 4) void k_recur(
    float* __restrict__ u, const float* __restrict__ ti,
    const float* __restrict__ Wall, const float* __restrict__ bWall,
    const float* __restrict__ Wd, const float* __restrict__ bWd)
{
    __shared__ float sm[R_TOT];
    const int s = blockIdx.x;
    const int tid = threadIdx.x;
    const int lq = tid >> 6, hh = tid & 63;
    float* ug = u + (size_t)s * NT * NL * NG;

    for (int i = tid; i < 1024; i += 320)
        *(float4*)&sm[R_WD + i * 4] = *(const float4*)(Wd + (size_t)s * 4096 + i * 4);
    if (tid < NL * NT) sm[R_TS + tid] = ti[(size_t)s * NL * NT + tid];
    sm[R_HS + tid] = 0.0f;
    sm[R_CS + tid] = 0.0f;
    const float bwd_r = bWd[(size_t)s * NH + hh];
    float wall_r[NH];
    float bwall_r = 0.0f, uc[NL];
    if (tid < NG) {
        bwall_r = bWall[(size_t)s * NG + tid];
        const float* wp = Wall + (size_t)s * (NH * NG) + tid;
        #pragma unroll
        for (int k = 0; k < NH; ++k) wall_r[k] = wp[(size_t)k * NG];
        #pragma unroll
        for (int l = 0; l < NL; ++l) uc[l] = ug[(size_t)l * NG + tid];
    }
    __syncthreads();

    for (int t = 0; t < NT; ++t) {
        float un[NL];
        if (tid < NG) {
            if (t + 1 < NT) {
                #pragma unroll
                for (int l = 0; l < NL; ++l)
                    un[l] = ug[(size_t)((t + 1) * NL + l) * NG + tid];
            } else {
                #pragma unroll
                for (int l = 0; l < NL; ++l) un[l] = 0.0f;
            }
            float gv[NL];
            #pragma unroll
            for (int l = 0; l < NL; ++l) gv[l] = bwall_r + uc[l];
            for (int k4 = 0; k4 < NH; k4 += 4) {
                const float w0 = wall_r[k4 + 0];
                const float w1 = wall_r[k4 + 1];
                const float w2 = wall_r[k4 + 2];
                const float w3 = wall_r[k4 + 3];
                #pragma unroll
                for (int l = 0; l < NL; ++l) {
                    float4 hv = *(const float4*)&sm[R_HS + l * NH + k4];
                    gv[l] += hv.x * w0 + hv.y * w1 + hv.z * w2 + hv.w * w3;
                }
            }
            #pragma unroll
            for (int l = 0; l < NL; ++l)
                sm[R_GATES + l * NG + tid] = sigf(gv[l]);
        }
        // c_s1 = tanh(c@Wd + bWd): c via wave-uniform float4 broadcast reads
        const float cold = sm[R_CS + tid];
        float ssum = bwd_r;
        for (int k4 = 0; k4 < NH; k4 += 4) {
            float4 cv = *(const float4*)&sm[R_CS + lq * NH + k4];
            ssum += cv.x * sm[R_WD + (k4 + 0) * NH + hh]
                  + cv.y * sm[R_WD + (k4 + 1) * NH + hh]
                  + cv.z * sm[R_WD + (k4 + 2) * NH + hh]
                  + cv.w * sm[R_WD + (k4 + 3) * NH + hh];
        }
        const float cs1 = tanhf(ssum);
        const float ca = cold - cs1 + cs1 * sm[R_TS + lq * NT + t];
        __syncthreads();
        {
            float f  = sm[R_GATES + lq * NG + hh];
            float ii = sm[R_GATES + lq * NG + 64 + hh];
            float oo = sm[R_GATES + lq * NG + 128 + hh];
            float ct = sm[R_GATES + lq * NG + 192 + hh];
            float cn = f * ca + ii * ct;
            sm[R_CS + tid] = cn;
            sm[R_HS + tid] = oo * tanhf(cn);
            ug[(size_t)(t * NL + lq) * NG + hh] = oo;       // o_t -> dead f-slot
        }
        __syncthreads();
        if (tid < NG) {
            #pragma unroll
            for (int l = 0; l < NL; ++l) uc[l] = un[l];
        }
    }
    ug[(size_t)(0 * NL + lq) * NG + 64 + hh] = sm[R_HS + tid];
}

// ---------------------------------------------------------------------------
// Kernel 2b (unchanged): attention + day LSTM + head.
// ---------------------------------------------------------------------------
#define P_W1    0
#define P_W2    4096
#define P_FULLO 8192
#define P_HS    14592
#define P_TQ    14912
#define P_CA    15232
#define P_SC    15552
#define P_B0    15652
#define P_B1    15716
#define P_BVV   15780
#define P_BV1   15844
#define P_TOT   15848

__global__ __launch_bounds__(320, 2) void k_post(
    const float* __restrict__ u,
    const float* __restrict__ W1, const float* __restrict__ b1,
    const float* __restrict__ W2, const float* __restrict__ b2,
    const float* __restrict__ V, const float* __restrict__ bV,
    const float* __restrict__ Wih, const float* __restrict__ bih,
    const float* __restrict__ bhh, const float* __restrict__ lin_w,
    const float* __restrict__ lin_b, float* __restrict__ out)
{
    __shared__ float sm[P_TOT];
    const int s = blockIdx.x;
    const int tid = threadIdx.x;
    const int lq = tid >> 6, hh = tid & 63;
    const int lane = hh;
    const float* ug = u + (size_t)s * NT * NL * NG;

    for (int i = tid; i < 1024; i += 320)
        *(float4*)&sm[P_W1 + i * 4] = *(const float4*)(W1 + (size_t)s * 4096 + i * 4);
    for (int i = tid; i < 1024; i += 320)
        *(float4*)&sm[P_W2 + i * 4] = *(const float4*)(W2 + (size_t)s * 4096 + i * 4);
    for (int i = tid; i < 1600; i += 320) {
        const int idx = i >> 4;
        const int l = idx / NT, t = idx % NT;
        const int k4 = (i & 15) * 4;
        *(float4*)&sm[P_FULLO + idx * NH + k4] =
            *(const float4*)(ug + (size_t)(t * NL + l) * NG + k4);
    }
    sm[P_HS + tid] = ug[(size_t)(0 * NL + lq) * NG + 64 + hh];
    if (tid < NH) {
        sm[P_B0 + tid]  = b1[(size_t)s * NH + tid];
        sm[P_B1 + tid]  = b2[(size_t)s * NH + tid];
        sm[P_BVV + tid] = V[(size_t)s * NH + tid];
    }
    if (tid == 0) sm[P_BV1] = bV[s];
    __syncthreads();

    {
        float qv = sm[P_B0 + hh];
        for (int k4 = 0; k4 < NH; k4 += 4) {
            float4 hv = *(const float4*)&sm[P_HS + lq * NH + k4];
            qv += hv.x * sm[P_W1 + (k4 + 0) * NH + hh]
                + hv.y * sm[P_W1 + (k4 + 1) * NH + hh]
                + hv.z * sm[P_W1 + (k4 + 2) * NH + hh]
                + hv.w * sm[P_W1 + (k4 + 3) * NH + hh];
        }
        sm[P_TQ + tid] = qv;
    }
    __syncthreads();

    for (int lt = lq; lt < NL * NT; lt += 5) {
        int l = lt / NT;
        float v = sm[P_TQ + l * NH + lane] + sm[P_B1 + lane];
        for (int k4 = 0; k4 < NH; k4 += 4) {
            float4 fv = *(const float4*)&sm[P_FULLO + lt * NH + k4];
            v += fv.x * sm[P_W2 + (k4 + 0) * NH + lane]
               + fv.y * sm[P_W2 + (k4 + 1) * NH + lane]
               + fv.z * sm[P_W2 + (k4 + 2) * NH + lane]
               + fv.w * sm[P_W2 + (k4 + 3) * NH + lane];
        }
        v = tanhf(v) * sm[P_BVV + lane];
        #pragma unroll
        for (int m = 32; m > 0; m >>= 1) v += __shfl_xor(v, m, 64);
        if (lane == 0) sm[P_SC + lt] = v + sm[P_BV1];
    }
    __syncthreads();

    if (tid < NL) {
        float mx = -1e30f;
        for (int t = 0; t < NT; ++t) mx = fmaxf(mx, sm[P_SC + tid * NT + t]);
        float sum = 0.0f;
        for (int t = 0; t < NT; ++t) {
            float e = expf(sm[P_SC + tid * NT + t] - mx);
            sm[P_SC + tid * NT + t] = e;
            sum += e;
        }
        float inv = 1.0f / sum;
        for (int t = 0; t < NT; ++t) sm[P_SC + tid * NT + t] *= inv;
    }
    __syncthreads();

    {
        float sv = 0.0f;
        #pragma unroll
        for (int t = 0; t < NT; ++t)
            sv += sm[P_SC + lq * NT + t] * sm[P_FULLO + (lq * NT + t) * NH + hh];
        sm[P_CA + tid] = sv;
    }
    __syncthreads();

    if (tid < NG) {
        float bsum = bih[(size_t)s * NG + tid] + bhh[(size_t)s * NG + tid];
        float d[NL];
        #pragma unroll
        for (int l = 0; l < NL; ++l) d[l] = bsum;
        for (int k = 0; k < NH; ++k) {
            float wk = Wih[((size_t)s * NH + k) * NG + tid];
            #pragma unroll
            for (int l = 0; l < NL; ++l)
                d[l] += sm[P_CA + l * NH + k] * wk;
        }
        #pragma unroll
        for (int l = 0; l < NL; ++l)
            sm[P_FULLO + l * NG + tid] = d[l];
    }
    __syncthreads();
    {
        float gi = sm[P_FULLO + lq * NG + hh];
        float gg = sm[P_FULLO + lq * NG + 128 + hh];
        float go = sm[P_FULLO + lq * NG + 192 + hh];
        float cd = sigf(gi) * tanhf(gg);
        sm[P_TQ + tid] = sigf(go) * tanhf(cd);
    }
    __syncthreads();

    {
        float v = sm[P_B0 + lane] + sm[P_B1 + lane];
        for (int k4 = 0; k4 < NH; k4 += 4) {
            float4 hv = *(const float4*)&sm[P_TQ + lq * NH + k4];
            v += hv.x * (sm[P_W1 + (k4 + 0) * NH + lane] + sm[P_W2 + (k4 + 0) * NH + lane])
               + hv.y * (sm[P_W1 + (k4 + 1) * NH + lane] + sm[P_W2 + (k4 + 1) * NH + lane])
               + hv.z * (sm[P_W1 + (k4 + 2) * NH + lane] + sm[P_W2 + (k4 + 2) * NH + lane])
               + hv.w * (sm[P_W1 + (k4 + 3) * NH + lane] + sm[P_W2 + (k4 + 3) * NH + lane]);
        }
        v = tanhf(v) * sm[P_BVV + lane];
        #pragma unroll
        for (int m = 32; m > 0; m >>= 1) v += __shfl_xor(v, m, 64);
        if (lane == 0) sm[P_SC + lq] = v + sm[P_BV1];
    }
    __syncthreads();
    if (tid == 0) {
        float mx = -1e30f;
        for (int l = 0; l < NL; ++l) mx = fmaxf(mx, sm[P_SC + l]);
        float sum = 0.0f;
        for (int l = 0; l < NL; ++l) {
            float e = expf(sm[P_SC + l] - mx);
            sm[P_SC + l] = e;
            sum += e;
        }
        float inv = 1.0f / sum;
        for (int l = 0; l < NL; ++l) sm[P_SC + l] *= inv;
    }
    __syncthreads();

    if (tid < NH) {
        float fv = 0.0f;
        #pragma unroll
        for (int l = 0; l < NL; ++l)
            fv += sm[P_SC + l] * sm[P_TQ + l * NH + tid];
        fv *= lin_w[tid];
        #pragma unroll
        for (int m = 32; m > 0; m >>= 1) fv += __shfl_xor(fv, m, 64);
        if (tid == 0) {
            float val = fv + lin_b[0];
            out[s] = val > 0.0f ? val : 0.01f * val;
        }
    }
}

extern "C" void kernel_launch(void* const* d_in, const int* in_sizes, int n_in,
                              void* d_out, int out_size, void* d_ws, size_t ws_size,
                              hipStream_t stream) {
    (void)in_sizes; (void)n_in; (void)out_size; (void)ws_size;
    const float* x     = (const float*)d_in[0];
    const float* ti    = (const float*)d_in[1];
    const float* Wall  = (const float*)d_in[2];
    const float* bWall = (const float*)d_in[3];
    const float* Uall  = (const float*)d_in[4];
    const float* bUall = (const float*)d_in[5];
    const float* Wd    = (const float*)d_in[6];
    const float* bWd   = (const float*)d_in[7];
    const float* W1    = (const float*)d_in[8];
    const float* b1    = (const float*)d_in[9];
    const float* W2    = (const float*)d_in[10];
    const float* b2    = (const float*)d_in[11];
    const float* V     = (const float*)d_in[12];
    const float* bV    = (const float*)d_in[13];
    const float* Wih   = (const float*)d_in[14];
    const float* bih   = (const float*)d_in[16];
    const float* bhh   = (const float*)d_in[17];
    const float* lin_w = (const float*)d_in[18];
    const float* lin_b = (const float*)d_in[19];
    float* out = (float*)d_out;
    float* u = (float*)d_ws;   // [S][T][L][NG] = 52.4 MB

    k_gemm_u<<<NS * 2, 512, 0, stream>>>(x, Uall, bUall, u);
    k_recur<<<NS, 320, 0, stream>>>(u, ti, Wall, bWall, Wd, bWd);
    k_post<<<NS, 320, 0, stream>>>(u, W1, b1, W2, b2, V, bV,
                                   Wih, bih, bhh, lin_w, lin_b, out);
}